// Round 1
// baseline (1267.553 us; speedup 1.0000x reference)
//
#include <hip/hip_runtime.h>

#define NB 4      // batch
#define NC 32     // width (channels)
#define NH 256
#define NW 256
#define NM 16     // modes per dim
constexpr int NPIX = NH * NW;                 // 65536
constexpr int NP = NB * NC * NPIX;            // floats per per-o tensor (8388608)
constexpr int ZPART_G = NB * NC * 4 * NM * NM * 2;  // 262144 floats per g
constexpr int ZMIX_G  = NB * NC * NM * NM * 2;      // 65536 floats per g

__device__ __forceinline__ float gelu_exact(float v) {
    return 0.5f * v * (1.0f + erff(v * 0.70710678118654752f));
}

// ---------------------------------------------------------------------------
// Forward truncated DFT: src rows -> partial Z(k,l) per 64-row chunk.
// grid: (chunk=4, c=32, gb=G*4), block 256.
// Thread mapping: phase1 (h_local = tid>>4, l = tid&15); phase2 (k = tid>>4, l).
// ---------------------------------------------------------------------------
template<bool LIFT>
__global__ __launch_bounds__(256) void fwd_kernel(
    const float* __restrict__ src,      // LIFT ? x[B,3,H,W] : xb[G,B,C,H,W]
    const float* __restrict__ lift_w,
    const float* __restrict__ lift_b,
    float* __restrict__ zpart)
{
    __shared__ float2 tw[256];
    __shared__ float  xr[16][NW];
    __shared__ float2 yw[16][NM];

    const int tid = threadIdx.x;
    const int chunk = blockIdx.x;
    const int c = blockIdx.y;
    const int gb = blockIdx.z;   // g*4 + b
    const int b = gb & 3;

    {
        float s, cs;
        sincospif((float)tid * (2.0f / 256.0f), &s, &cs);  // angle = 2*pi*tid/256
        tw[tid] = make_float2(cs, s);
    }

    float lw0 = 0.f, lw1 = 0.f, lw2 = 0.f, lb = 0.f;
    const float* sb;
    if (LIFT) {
        lw0 = lift_w[c * 3 + 0]; lw1 = lift_w[c * 3 + 1]; lw2 = lift_w[c * 3 + 2];
        lb = lift_b[c];
        sb = src + (size_t)b * 3 * NPIX;
    } else {
        sb = src + ((size_t)gb * NC + c) * NPIX;
    }

    const int hl = tid >> 4;   // 0..15
    const int l  = tid & 15;
    const int k  = hl;

    float zr = 0.f, zi = 0.f;

    for (int rb = 0; rb < 4; ++rb) {
        const int h0 = chunk * 64 + rb * 16;
        __syncthreads();
        // load 16 rows (lifted if LIFT)
        for (int j = 0; j < 16; ++j) {
            const int h = h0 + j;
            float v;
            if (LIFT) {
                const float* p = sb + h * NW + tid;
                v = lw0 * p[0] + lw1 * p[NPIX] + lw2 * p[2 * NPIX] + lb;
            } else {
                v = sb[h * NW + tid];
            }
            xr[j][tid] = v;
        }
        __syncthreads();
        // phase 1: Yw[hl][l] = sum_w x[hl][w] * e^{-2pi i l w/256}
        float yr = 0.f, yi = 0.f;
        {
            int m = 0;
            const float4* xrow = (const float4*)(&xr[hl][0]);
            #pragma unroll 4
            for (int w4 = 0; w4 < NW / 4; ++w4) {
                const float4 xv = xrow[w4];
                const float2 t0 = tw[m]; m = (m + l) & 255;
                const float2 t1 = tw[m]; m = (m + l) & 255;
                const float2 t2 = tw[m]; m = (m + l) & 255;
                const float2 t3 = tw[m]; m = (m + l) & 255;
                yr += xv.x * t0.x + xv.y * t1.x + xv.z * t2.x + xv.w * t3.x;
                yi -= xv.x * t0.y + xv.y * t1.y + xv.z * t2.y + xv.w * t3.y;
            }
        }
        yw[hl][l] = make_float2(yr, yi);
        __syncthreads();
        // phase 2: Z(k,l) += sum_h Yw[h][l] * e^{-2pi i k h/256}
        int m2 = (k * h0) & 255;
        #pragma unroll
        for (int hh = 0; hh < 16; ++hh) {
            const float2 y = yw[hh][l];
            const float2 t = tw[m2];
            zr += y.x * t.x + y.y * t.y;
            zi += y.y * t.x - y.x * t.y;
            m2 = (m2 + k) & 255;
        }
    }
    const float sc = 1.0f / 256.0f;   // ortho norm of forward rfft2
    const int idx = ((gb * NC + c) * 4 + chunk) * 256 + tid;
    zpart[idx * 2 + 0] = zr * sc;
    zpart[idx * 2 + 1] = zi * sc;
}

// ---------------------------------------------------------------------------
// Mode mix: reduce chunk partials, complex channel matmul per (k,l) mode.
// grid: (mode=256, g=G), block 128 = (b=4) x (oc=32).
// ---------------------------------------------------------------------------
__global__ __launch_bounds__(128) void mix_kernel(
    const float* __restrict__ zpart,
    float* __restrict__ zmix,
    const float* __restrict__ wr,
    const float* __restrict__ wi,
    int o0, int n)
{
    __shared__ float zs[NB][NC][2];
    const int tid = threadIdx.x;
    const int mode = blockIdx.x;   // k*16 + l
    const int g = blockIdx.y;

    #pragma unroll
    for (int e = 0; e < 2; ++e) {
        const int item = tid * 2 + e;          // 0..255 = b*64 + i*2 + comp
        const int bb_ = item >> 6;
        const int i = (item >> 1) & 31;
        const int comp = item & 1;
        float s = 0.f;
        const int base = ((g * NB + bb_) * NC + i) * 4;
        #pragma unroll
        for (int ch = 0; ch < 4; ++ch)
            s += zpart[(base + ch) * 512 + mode * 2 + comp];
        zs[bb_][i][comp] = s;
    }
    __syncthreads();

    const int b = tid >> 5;
    const int oc = tid & 31;
    const int o = o0 + g;
    const float* wrb = wr + (size_t)(o * 4 + n) * NC * NC * 256;
    const float* wib = wi + (size_t)(o * 4 + n) * NC * NC * 256;
    float orr = 0.f, oii = 0.f;
    for (int i = 0; i < NC; ++i) {
        const float zrv = zs[b][i][0];
        const float ziv = zs[b][i][1];
        const float wrv = wrb[(i * NC + oc) * 256 + mode];
        const float wiv = wib[(i * NC + oc) * 256 + mode];
        orr += zrv * wrv - ziv * wiv;
        oii += zrv * wiv + ziv * wrv;
    }
    const int oidx = ((g * NB + b) * NC + oc) * 256 + mode;
    zmix[oidx * 2 + 0] = orr;
    zmix[oidx * 2 + 1] = oii;
}

// ---------------------------------------------------------------------------
// Inverse transform + bypass + GELU (+ fused projection on last layer).
// grid: (h=256, gb=G*4), block 256 (thread = pixel w).
// ---------------------------------------------------------------------------
template<bool LIFT, bool FINAL>
__global__ __launch_bounds__(256) void inv_kernel(
    const float* __restrict__ zmix,
    const float* __restrict__ src,     // x if LIFT else xb
    const float* __restrict__ byp_w,
    const float* __restrict__ byp_b,
    const float* __restrict__ lift_w,
    const float* __restrict__ lift_b,
    const float* __restrict__ proj_w,
    const float* __restrict__ proj_b,
    float* __restrict__ dst,           // next xb, or d_out if FINAL
    int o0, int n)
{
    __shared__ float2 tw[256];
    __shared__ float2 tmps[NC][NM];
    __shared__ float  bwl[NC * NC];
    __shared__ float  xls[NC * NW];
    __shared__ float  bbl[NC];          // bb, or effective bias if LIFT
    __shared__ float  bweffs[NC * 3];   // LIFT only
    __shared__ float  pwl[NC];

    const int tid = threadIdx.x;
    const int h = blockIdx.x;
    const int gb = blockIdx.y;
    const int g = gb >> 2, b = gb & 3;
    const int o = o0 + g;

    {
        float s, cs;
        sincospif((float)tid * (2.0f / 256.0f), &s, &cs);
        tw[tid] = make_float2(cs, s);
    }

    const float* bwp = byp_w + (size_t)(o * 4 + n) * NC * NC;
    for (int j = tid; j < NC * NC; j += 256) bwl[j] = bwp[j];
    if (tid < NC) {
        bbl[tid] = byp_b[(o * 4 + n) * NC + tid];
        if (FINAL) pwl[tid] = proj_w[tid];
    }
    __syncthreads();

    if (LIFT) {
        // fold lift into bypass: bweff[oc][j] = sum_ic bw[oc][ic]*lw[ic][j]
        if (tid < 96) {
            const int oc = tid / 3, j = tid % 3;
            float s = 0.f;
            for (int ic = 0; ic < NC; ++ic) s += bwl[oc * NC + ic] * lift_w[ic * 3 + j];
            bweffs[oc * 3 + j] = s;
        } else if (tid < 128) {
            const int oc = tid - 96;
            float s = bbl[oc];
            for (int ic = 0; ic < NC; ++ic) s += bwl[oc * NC + ic] * lift_b[ic];
            bbl[oc] = s;   // only this thread touches bbl[oc] here
        }
        __syncthreads();
    }

    // phase A: tmps[c][l] = s_l * sum_k Zo[c,k,l] * e^{+2pi i k h/256}
    for (int it = tid; it < NC * NM; it += 256) {
        const int c = it >> 4, l = it & 15;
        const float sl = (l == 0 ? 1.0f : 2.0f) / 256.0f;  // ortho inverse + hermitian doubling
        const float* zp = zmix + ((size_t)(gb * NC + c) * 256 + l) * 2;
        float tr = 0.f, ti = 0.f;
        int m = 0;
        #pragma unroll
        for (int k = 0; k < NM; ++k) {
            const float zrv = zp[k * 32 + 0];
            const float ziv = zp[k * 32 + 1];
            const float2 t = tw[m];
            tr += zrv * t.x - ziv * t.y;
            ti += zrv * t.y + ziv * t.x;
            m = (m + h) & 255;
        }
        tmps[c][l] = make_float2(tr * sl, ti * sl);
    }

    // phase B: stage the x row(s) for the bypass
    if (LIFT) {
        for (int ic = 0; ic < 3; ++ic)
            xls[ic * NW + tid] = src[((size_t)b * 3 + ic) * NPIX + h * NW + tid];
    } else {
        const float* sp = src + ((size_t)gb * NC) * NPIX + h * NW + tid;
        for (int ic = 0; ic < NC; ++ic)
            xls[ic * NW + tid] = sp[ic * NPIX];
    }
    __syncthreads();

    // phase C: per-pixel inverse-W + bypass + GELU (+ proj)
    const int w = tid;
    float2 cw[NM];
    {
        int m = 0;
        #pragma unroll
        for (int l = 0; l < NM; ++l) { cw[l] = tw[m]; m = (m + w) & 255; }
    }
    float xv[NC];
    float x0v = 0.f, x1v = 0.f, x2v = 0.f;
    if (LIFT) {
        x0v = xls[0 * NW + w]; x1v = xls[1 * NW + w]; x2v = xls[2 * NW + w];
    } else {
        #pragma unroll
        for (int ic = 0; ic < NC; ++ic) xv[ic] = xls[ic * NW + w];
    }
    float acc = 0.f;
    float* dbase = FINAL ? nullptr : (dst + ((size_t)gb * NC) * NPIX + h * NW + w);
    for (int c = 0; c < NC; ++c) {
        float sp = 0.f;
        #pragma unroll
        for (int l = 0; l < NM; ++l) {
            const float2 tm = tmps[c][l];
            sp += tm.x * cw[l].x - tm.y * cw[l].y;
        }
        float bp;
        if (LIFT) {
            bp = bbl[c] + x0v * bweffs[c * 3 + 0] + x1v * bweffs[c * 3 + 1] + x2v * bweffs[c * 3 + 2];
        } else {
            bp = bbl[c];
            #pragma unroll
            for (int ic = 0; ic < NC; ++ic) bp += xv[ic] * bwl[c * NC + ic];
        }
        const float v = sp + bp;
        const float gl = gelu_exact(v);
        if (FINAL) acc += gl * pwl[c];
        else dbase[c * NPIX] = gl;
    }
    if (FINAL) {
        dst[(((size_t)b * 4 + o) * NH + h) * NW + w] = acc + proj_b[0];
    }
}

// ---------------------------------------------------------------------------
extern "C" void kernel_launch(void* const* d_in, const int* in_sizes, int n_in,
                              void* d_out, int out_size, void* d_ws, size_t ws_size,
                              hipStream_t stream)
{
    const float* x      = (const float*)d_in[0];
    const float* lift_w = (const float*)d_in[1];
    const float* lift_b = (const float*)d_in[2];
    const float* wr     = (const float*)d_in[3];
    const float* wi     = (const float*)d_in[4];
    const float* byp_w  = (const float*)d_in[5];
    const float* byp_b  = (const float*)d_in[6];
    const float* proj_w = (const float*)d_in[7];
    const float* proj_b = (const float*)d_in[8];
    float* out = (float*)d_out;
    float* ws  = (float*)d_ws;

    // Pick the largest o-batch G in {4,2,1} that fits the workspace.
    int G = 4;
    while (G > 1) {
        const size_t need = ((size_t)2 * G * NP + (size_t)G * ZPART_G + (size_t)G * ZMIX_G) * sizeof(float);
        if (need <= ws_size) break;
        G >>= 1;
    }

    float* bufA  = ws;
    float* bufB  = bufA + (size_t)G * NP;
    float* zpart = bufB + (size_t)G * NP;
    float* zmix  = zpart + (size_t)G * ZPART_G;

    for (int o0 = 0; o0 < 4; o0 += G) {
        const float* rd = nullptr;
        float* wrb = bufA;
        for (int n = 0; n < 4; ++n) {
            const bool lift = (n == 0);
            const bool fin  = (n == 3);
            const float* src = lift ? x : rd;

            dim3 fgrid(4, NC, G * NB);
            if (lift) fwd_kernel<true><<<fgrid, 256, 0, stream>>>(src, lift_w, lift_b, zpart);
            else      fwd_kernel<false><<<fgrid, 256, 0, stream>>>(src, lift_w, lift_b, zpart);

            mix_kernel<<<dim3(256, G), 128, 0, stream>>>(zpart, zmix, wr, wi, o0, n);

            dim3 igrid(NH, G * NB);
            if (fin) {
                inv_kernel<false, true><<<igrid, 256, 0, stream>>>(
                    zmix, src, byp_w, byp_b, lift_w, lift_b, proj_w, proj_b, out, o0, n);
            } else if (lift) {
                inv_kernel<true, false><<<igrid, 256, 0, stream>>>(
                    zmix, src, byp_w, byp_b, lift_w, lift_b, proj_w, proj_b, wrb, o0, n);
            } else {
                inv_kernel<false, false><<<igrid, 256, 0, stream>>>(
                    zmix, src, byp_w, byp_b, lift_w, lift_b, proj_w, proj_b, wrb, o0, n);
            }
            rd = wrb;
            wrb = (wrb == bufA) ? bufB : bufA;
        }
    }
}

// Round 2
// 1141.253 us; speedup vs baseline: 1.1107x; 1.1107x over previous
//
#include <hip/hip_runtime.h>

#define NB 4      // batch
#define NC 32     // width (channels)
#define NH 256
#define NW 256
#define NM 16     // modes per dim
constexpr int NPIX = NH * NW;                 // 65536
constexpr int NP = NB * NC * NPIX;            // floats per per-o tensor
constexpr int ZG = NB * NC * NM * NM * 2;     // floats per g for zred/zmix (65536)

__device__ __forceinline__ float gelu_exact(float v) {
    return 0.5f * v * (1.0f + erff(v * 0.70710678118654752f));
}

// ---------------------------------------------------------------------------
// Forward truncated DFT: one block per (c, gb) does all 256 rows, writes the
// fully reduced Z(k,l). Register twiddles: e(-wl) = e(-16*a*l) * e(-b*l),
// Bl[b] held in VGPRs; per 16 pixels: 4 ds_read_b128 + 1 ds_read_b64 + ~40 FMA.
// grid: LIFT ? (32, 4) : (32, G*4), block 256.
// ---------------------------------------------------------------------------
template<bool LIFT>
__global__ __launch_bounds__(256) void fwd_kernel(
    const float* __restrict__ src,      // LIFT ? x[B,3,H,W] : xb[G,B,C,H,W]
    const float* __restrict__ lift_w,
    const float* __restrict__ lift_b,
    float* __restrict__ zred)           // [gb][c][mode][2]
{
    __shared__ float2 tw[256];
    __shared__ float  xr[16][260];      // +4 pad: de-conflicts b128 reads
    __shared__ float2 yw[16][16];

    const int tid = threadIdx.x;
    const int c  = blockIdx.x;
    const int gb = blockIdx.y;          // LIFT: gb == b
    const int b  = gb & 3;

    {
        float s, cs;
        sincospif((float)tid * (2.0f / 256.0f), &s, &cs);
        tw[tid] = make_float2(cs, s);
    }
    __syncthreads();

    const int hl = tid >> 4;   // row within 16-row tile; also k in phase 2
    const int l  = tid & 15;

    // register twiddles: Bl[b2] = e^{-2pi i * b2 * l / 256}
    float Blr[16], Bli[16];
    #pragma unroll
    for (int b2 = 0; b2 < 16; ++b2) {
        const float2 t = tw[(b2 * l) & 255];
        Blr[b2] = t.x; Bli[b2] = -t.y;
    }

    float lw0 = 0.f, lw1 = 0.f, lw2 = 0.f, lb = 0.f;
    const float* sb;
    if (LIFT) {
        lw0 = lift_w[c * 3 + 0]; lw1 = lift_w[c * 3 + 1]; lw2 = lift_w[c * 3 + 2];
        lb = lift_b[c];
        sb = src + (size_t)b * 3 * NPIX;
    } else {
        sb = src + ((size_t)gb * NC + c) * NPIX;
    }

    float zr = 0.f, zi = 0.f;

    for (int rb = 0; rb < 16; ++rb) {
        const int h0 = rb * 16;
        __syncthreads();
        #pragma unroll
        for (int j = 0; j < 16; ++j) {
            const int h = h0 + j;
            float v;
            if (LIFT) {
                const float* p = sb + h * NW + tid;
                v = lw0 * p[0] + lw1 * p[NPIX] + lw2 * p[2 * NPIX] + lb;
            } else {
                v = sb[h * NW + tid];
            }
            xr[j][tid] = v;
        }
        __syncthreads();

        // phase 1: Y[l] for row hl
        float Yr = 0.f, Yi = 0.f;
        {
            const float* xrow = &xr[hl][0];
            #pragma unroll 2
            for (int a = 0; a < 16; ++a) {
                const float4 x0 = *(const float4*)(xrow + a * 16 + 0);
                const float4 x1 = *(const float4*)(xrow + a * 16 + 4);
                const float4 x2 = *(const float4*)(xrow + a * 16 + 8);
                const float4 x3 = *(const float4*)(xrow + a * 16 + 12);
                const float Sr =
                    x0.x * Blr[0]  + x0.y * Blr[1]  + x0.z * Blr[2]  + x0.w * Blr[3] +
                    x1.x * Blr[4]  + x1.y * Blr[5]  + x1.z * Blr[6]  + x1.w * Blr[7] +
                    x2.x * Blr[8]  + x2.y * Blr[9]  + x2.z * Blr[10] + x2.w * Blr[11] +
                    x3.x * Blr[12] + x3.y * Blr[13] + x3.z * Blr[14] + x3.w * Blr[15];
                const float Si =
                    x0.x * Bli[0]  + x0.y * Bli[1]  + x0.z * Bli[2]  + x0.w * Bli[3] +
                    x1.x * Bli[4]  + x1.y * Bli[5]  + x1.z * Bli[6]  + x1.w * Bli[7] +
                    x2.x * Bli[8]  + x2.y * Bli[9]  + x2.z * Bli[10] + x2.w * Bli[11] +
                    x3.x * Bli[12] + x3.y * Bli[13] + x3.z * Bli[14] + x3.w * Bli[15];
                const float2 A = tw[(a * 16 * l) & 255];   // e^{+i phi}; use conj
                Yr += Sr * A.x + Si * A.y;
                Yi += Si * A.x - Sr * A.y;
            }
        }
        yw[hl][l] = make_float2(Yr, Yi);
        __syncthreads();

        // phase 2: Z(k=hl, l) += sum_h Y[h][l] * e^{-2pi i k h/256}
        int m2 = (hl * h0) & 255;
        #pragma unroll
        for (int hh = 0; hh < 16; ++hh) {
            const float2 y = yw[hh][l];
            const float2 t = tw[m2];
            zr += y.x * t.x + y.y * t.y;
            zi += y.y * t.x - y.x * t.y;
            m2 = (m2 + hl) & 255;
        }
    }

    const float sc = 1.0f / 256.0f;     // ortho norm of forward rfft2
    const int idx = (gb * NC + c) * 256 + tid;   // tid == k*16+l
    zred[idx * 2 + 0] = zr * sc;
    zred[idx * 2 + 1] = zi * sc;
}

// ---------------------------------------------------------------------------
// Mode mix: complex channel matmul per (k,l). thread = mode -> all loads
// coalesced. grid: (oc=32, G), block 256.
// ---------------------------------------------------------------------------
__global__ __launch_bounds__(256) void mix_kernel(
    const float* __restrict__ zred,
    float* __restrict__ zmix,
    const float* __restrict__ wr,
    const float* __restrict__ wi,
    int o0, int n, int zgmul)           // zgmul=0 when zred is g-independent (n==0)
{
    const int mode = threadIdx.x;
    const int oc = blockIdx.x;
    const int g  = blockIdx.y;
    const int o  = o0 + g;
    const int zg = zgmul * g;

    const float* wrb = wr + (size_t)(o * 4 + n) * NC * NC * 256;
    const float* wib = wi + (size_t)(o * 4 + n) * NC * NC * 256;

    float orr[NB] = {0.f, 0.f, 0.f, 0.f};
    float oii[NB] = {0.f, 0.f, 0.f, 0.f};

    for (int i = 0; i < NC; ++i) {
        const float wrv = wrb[(i * NC + oc) * 256 + mode];
        const float wiv = wib[(i * NC + oc) * 256 + mode];
        #pragma unroll
        for (int b = 0; b < NB; ++b) {
            const float2 z = *(const float2*)&zred[(((zg * NB + b) * NC + i) * 256 + mode) * 2];
            orr[b] += z.x * wrv - z.y * wiv;
            oii[b] += z.x * wiv + z.y * wrv;
        }
    }
    #pragma unroll
    for (int b = 0; b < NB; ++b) {
        float2* dst = (float2*)&zmix[(((g * NB + b) * NC + oc) * 256 + mode) * 2];
        *dst = make_float2(orr[b], oii[b]);
    }
}

// ---------------------------------------------------------------------------
// Inverse transform + bypass + GELU (+ fused projection on last layer).
// Bypass weights/bias/proj come in via wave-uniform global reads (scalar
// loads); tmps read as broadcast float4; x read straight to registers.
// grid: (h=256, gb=G*4), block 256 (thread = pixel w).
// ---------------------------------------------------------------------------
template<bool LIFT, bool FINAL>
__global__ __launch_bounds__(256) void inv_kernel(
    const float* __restrict__ zmix,
    const float* __restrict__ src,     // x if LIFT else xb
    const float* __restrict__ byp_w,
    const float* __restrict__ byp_b,
    const float* __restrict__ lift_w,
    const float* __restrict__ lift_b,
    const float* __restrict__ proj_w,
    const float* __restrict__ proj_b,
    float* __restrict__ dst,           // next xb, or d_out if FINAL
    int o0, int n)
{
    __shared__ float2 tw[256];
    __shared__ float2 tmps[NC][NM];
    __shared__ float  bbl[NC];          // LIFT only: folded bias
    __shared__ float  bweffs[NC * 3];   // LIFT only

    const int tid = threadIdx.x;
    const int h = blockIdx.x;
    const int gb = blockIdx.y;
    const int g = gb >> 2, b = gb & 3;
    const int o = o0 + g;

    {
        float s, cs;
        sincospif((float)tid * (2.0f / 256.0f), &s, &cs);
        tw[tid] = make_float2(cs, s);
    }

    const float* bwp = byp_w + (size_t)(o * 4 + n) * NC * NC;
    const float* bbp = byp_b + (o * 4 + n) * NC;

    if (LIFT) {
        // fold lift into bypass: bweff[oc][j] = sum_ic bw[oc][ic]*lw[ic][j]
        if (tid < 96) {
            const int oc = tid / 3, j = tid % 3;
            float s = 0.f;
            for (int ic = 0; ic < NC; ++ic) s += bwp[oc * NC + ic] * lift_w[ic * 3 + j];
            bweffs[oc * 3 + j] = s;
        } else if (tid < 128) {
            const int oc = tid - 96;
            float s = bbp[oc];
            for (int ic = 0; ic < NC; ++ic) s += bwp[oc * NC + ic] * lift_b[ic];
            bbl[oc] = s;
        }
    }
    __syncthreads();

    // phase A: tmps[c][l] = s_l * sum_k Z[c,k,l] * e^{+2pi i k h/256}
    #pragma unroll
    for (int rep = 0; rep < 2; ++rep) {
        const int it = rep * 256 + tid;
        const int c = it >> 4, l = it & 15;
        const float sl = (l == 0 ? 1.0f : 2.0f) / 256.0f;  // ortho inv + hermitian
        const float* zp = zmix + ((size_t)(gb * NC + c) * 256 + l) * 2;
        float tr = 0.f, ti = 0.f;
        int m = 0;
        #pragma unroll
        for (int k = 0; k < NM; ++k) {
            const float2 z = *(const float2*)(zp + k * 32);
            const float2 t = tw[m];
            tr += z.x * t.x - z.y * t.y;
            ti += z.x * t.y + z.y * t.x;
            m = (m + h) & 255;
        }
        tmps[c][l] = make_float2(tr * sl, ti * sl);
    }
    __syncthreads();

    // phase C: per-pixel inverse-W + bypass + GELU (+ proj)
    const int w = tid;
    float2 cw[NM];
    {
        int m = 0;
        #pragma unroll
        for (int l = 0; l < NM; ++l) { cw[l] = tw[m]; m = (m + w) & 255; }
    }
    float xv[NC];
    float x0v = 0.f, x1v = 0.f, x2v = 0.f;
    if (LIFT) {
        const float* sp = src + (size_t)b * 3 * NPIX + h * NW + w;
        x0v = sp[0]; x1v = sp[NPIX]; x2v = sp[2 * NPIX];
    } else {
        const float* sp = src + ((size_t)gb * NC) * NPIX + h * NW + w;
        #pragma unroll
        for (int ic = 0; ic < NC; ++ic) xv[ic] = sp[ic * NPIX];
    }

    float acc = 0.f;
    float* dbase = FINAL ? nullptr : (dst + ((size_t)gb * NC) * NPIX + h * NW + w);
    for (int c = 0; c < NC; ++c) {
        float sp = 0.f;
        const float4* tp = (const float4*)&tmps[c][0];
        #pragma unroll
        for (int l4 = 0; l4 < 8; ++l4) {
            const float4 t4 = tp[l4];   // (re0,im0,re1,im1)
            sp += t4.x * cw[2 * l4].x     - t4.y * cw[2 * l4].y
                + t4.z * cw[2 * l4 + 1].x - t4.w * cw[2 * l4 + 1].y;
        }
        float bp;
        if (LIFT) {
            bp = bbl[c] + x0v * bweffs[c * 3 + 0] + x1v * bweffs[c * 3 + 1] + x2v * bweffs[c * 3 + 2];
        } else {
            bp = bbp[c];                       // uniform -> scalar load
            const float* bwrow = bwp + c * NC; // uniform -> scalar loads
            #pragma unroll
            for (int ic = 0; ic < NC; ++ic) bp += xv[ic] * bwrow[ic];
        }
        const float v = sp + bp;
        const float gl = gelu_exact(v);
        if (FINAL) acc += gl * proj_w[c];      // uniform -> scalar load
        else dbase[c * NPIX] = gl;
    }
    if (FINAL) {
        dst[(((size_t)b * 4 + o) * NH + h) * NW + w] = acc + proj_b[0];
    }
}

// ---------------------------------------------------------------------------
extern "C" void kernel_launch(void* const* d_in, const int* in_sizes, int n_in,
                              void* d_out, int out_size, void* d_ws, size_t ws_size,
                              hipStream_t stream)
{
    const float* x      = (const float*)d_in[0];
    const float* lift_w = (const float*)d_in[1];
    const float* lift_b = (const float*)d_in[2];
    const float* wr     = (const float*)d_in[3];
    const float* wi     = (const float*)d_in[4];
    const float* byp_w  = (const float*)d_in[5];
    const float* byp_b  = (const float*)d_in[6];
    const float* proj_w = (const float*)d_in[7];
    const float* proj_b = (const float*)d_in[8];
    float* out = (float*)d_out;
    float* ws  = (float*)d_ws;

    // Pick the largest o-batch G in {4,2,1} that fits the workspace.
    int G = 4;
    while (G > 1) {
        const size_t need = ((size_t)2 * G * NP + (size_t)2 * G * ZG) * sizeof(float);
        if (need <= ws_size) break;
        G >>= 1;
    }

    float* bufA = ws;
    float* bufB = bufA + (size_t)G * NP;
    float* zred = bufB + (size_t)G * NP;
    float* zmix = zred + (size_t)G * ZG;

    for (int o0 = 0; o0 < 4; o0 += G) {
        const float* rd = nullptr;
        float* wrbuf = bufA;
        for (int n = 0; n < 4; ++n) {
            const bool lift = (n == 0);
            const bool fin  = (n == 3);
            const float* src = lift ? x : rd;

            if (lift) {
                // spectrum of x0 is g-independent: compute once over (c, b)
                fwd_kernel<true><<<dim3(NC, NB), 256, 0, stream>>>(src, lift_w, lift_b, zred);
            } else {
                fwd_kernel<false><<<dim3(NC, G * NB), 256, 0, stream>>>(src, lift_w, lift_b, zred);
            }

            mix_kernel<<<dim3(NC, G), 256, 0, stream>>>(zred, zmix, wr, wi, o0, n, lift ? 0 : 1);

            dim3 igrid(NH, G * NB);
            if (fin) {
                inv_kernel<false, true><<<igrid, 256, 0, stream>>>(
                    zmix, src, byp_w, byp_b, lift_w, lift_b, proj_w, proj_b, out, o0, n);
            } else if (lift) {
                inv_kernel<true, false><<<igrid, 256, 0, stream>>>(
                    zmix, src, byp_w, byp_b, lift_w, lift_b, proj_w, proj_b, wrbuf, o0, n);
            } else {
                inv_kernel<false, false><<<igrid, 256, 0, stream>>>(
                    zmix, src, byp_w, byp_b, lift_w, lift_b, proj_w, proj_b, wrbuf, o0, n);
            }
            rd = wrbuf;
            wrbuf = (wrbuf == bufA) ? bufB : bufA;
        }
    }
}

// Round 3
// 787.482 us; speedup vs baseline: 1.6096x; 1.4492x over previous
//
#include <hip/hip_runtime.h>

#define NB 4      // batch
#define NC 32     // width (channels)
#define NH 256
#define NW 256
#define NM 16     // modes per dim
constexpr int NPIX = NH * NW;                 // 65536
constexpr int NP = NB * NC * NPIX;            // floats per per-o tensor
constexpr int ZG = NB * NC * NM * NM * 2;     // floats per g for zred/zmix (65536)

typedef short bf16x8 __attribute__((ext_vector_type(8)));
typedef float f32x4  __attribute__((ext_vector_type(4)));
typedef unsigned short u16;

#define MFMA16(a, b, c) __builtin_amdgcn_mfma_f32_16x16x32_bf16(a, b, c, 0, 0, 0)

__device__ __forceinline__ u16 f2bf(float f) {
    unsigned u = __float_as_uint(f);
    u += 0x7FFFu + ((u >> 16) & 1u);
    return (u16)(u >> 16);
}
__device__ __forceinline__ float bf2f(u16 h) {
    return __uint_as_float(((unsigned)h) << 16);
}

// fast erf (A&S 7.1.26, |err| <= 1.5e-7) based exact-GELU
__device__ __forceinline__ float gelu_fast(float v) {
    const float ax = fabsf(v) * 0.70710678118654752f;
    const float t = __builtin_amdgcn_rcpf(1.0f + 0.3275911f * ax);
    const float y = t * (0.254829592f + t * (-0.284496736f + t * (1.421413741f +
                    t * (-1.453152027f + t * 1.061405429f))));
    const float e = __expf(-ax * ax);
    float er = 1.0f - y * e;
    er = copysignf(er, v);
    return 0.5f * v * (1.0f + er);
}

// ---------------------------------------------------------------------------
// CW prep: constant inverse-DFT B-matrix, bf16 hi/lo split, layout [n=256][k=32]
// k<16: cos(2*pi*k*n/256); k>=16: sin(2*pi*(k-16)*n/256).
// ---------------------------------------------------------------------------
__global__ __launch_bounds__(256) void cw_prep(u16* __restrict__ cwhi, u16* __restrict__ cwlo) {
    const int id = blockIdx.x * 256 + threadIdx.x;   // 0..8191
    const int nn = id >> 5, k = id & 31;
    const int m = ((k & 15) * nn) & 255;
    float s, c;
    sincospif((float)m * (2.0f / 256.0f), &s, &c);
    const float v = (k < 16) ? c : s;
    const u16 hi = f2bf(v);
    cwhi[id] = hi;
    cwlo[id] = f2bf(v - bf2f(hi));
}

// ---------------------------------------------------------------------------
// Forward truncated DFT (unchanged from round 2 — known correct).
// ---------------------------------------------------------------------------
template<bool LIFT>
__global__ __launch_bounds__(256) void fwd_kernel(
    const float* __restrict__ src,
    const float* __restrict__ lift_w,
    const float* __restrict__ lift_b,
    float* __restrict__ zred)
{
    __shared__ float2 tw[256];
    __shared__ float  xr[16][260];
    __shared__ float2 yw[16][16];

    const int tid = threadIdx.x;
    const int c  = blockIdx.x;
    const int gb = blockIdx.y;
    const int b  = gb & 3;

    {
        float s, cs;
        sincospif((float)tid * (2.0f / 256.0f), &s, &cs);
        tw[tid] = make_float2(cs, s);
    }
    __syncthreads();

    const int hl = tid >> 4;
    const int l  = tid & 15;

    float Blr[16], Bli[16];
    #pragma unroll
    for (int b2 = 0; b2 < 16; ++b2) {
        const float2 t = tw[(b2 * l) & 255];
        Blr[b2] = t.x; Bli[b2] = -t.y;
    }

    float lw0 = 0.f, lw1 = 0.f, lw2 = 0.f, lb = 0.f;
    const float* sb;
    if (LIFT) {
        lw0 = lift_w[c * 3 + 0]; lw1 = lift_w[c * 3 + 1]; lw2 = lift_w[c * 3 + 2];
        lb = lift_b[c];
        sb = src + (size_t)b * 3 * NPIX;
    } else {
        sb = src + ((size_t)gb * NC + c) * NPIX;
    }

    float zr = 0.f, zi = 0.f;

    for (int rb = 0; rb < 16; ++rb) {
        const int h0 = rb * 16;
        __syncthreads();
        #pragma unroll
        for (int j = 0; j < 16; ++j) {
            const int h = h0 + j;
            float v;
            if (LIFT) {
                const float* p = sb + h * NW + tid;
                v = lw0 * p[0] + lw1 * p[NPIX] + lw2 * p[2 * NPIX] + lb;
            } else {
                v = sb[h * NW + tid];
            }
            xr[j][tid] = v;
        }
        __syncthreads();

        float Yr = 0.f, Yi = 0.f;
        {
            const float* xrow = &xr[hl][0];
            #pragma unroll 2
            for (int a = 0; a < 16; ++a) {
                const float4 x0 = *(const float4*)(xrow + a * 16 + 0);
                const float4 x1 = *(const float4*)(xrow + a * 16 + 4);
                const float4 x2 = *(const float4*)(xrow + a * 16 + 8);
                const float4 x3 = *(const float4*)(xrow + a * 16 + 12);
                const float Sr =
                    x0.x * Blr[0]  + x0.y * Blr[1]  + x0.z * Blr[2]  + x0.w * Blr[3] +
                    x1.x * Blr[4]  + x1.y * Blr[5]  + x1.z * Blr[6]  + x1.w * Blr[7] +
                    x2.x * Blr[8]  + x2.y * Blr[9]  + x2.z * Blr[10] + x2.w * Blr[11] +
                    x3.x * Blr[12] + x3.y * Blr[13] + x3.z * Blr[14] + x3.w * Blr[15];
                const float Si =
                    x0.x * Bli[0]  + x0.y * Bli[1]  + x0.z * Bli[2]  + x0.w * Bli[3] +
                    x1.x * Bli[4]  + x1.y * Bli[5]  + x1.z * Bli[6]  + x1.w * Bli[7] +
                    x2.x * Bli[8]  + x2.y * Bli[9]  + x2.z * Bli[10] + x2.w * Bli[11] +
                    x3.x * Bli[12] + x3.y * Bli[13] + x3.z * Bli[14] + x3.w * Bli[15];
                const float2 A = tw[(a * 16 * l) & 255];
                Yr += Sr * A.x + Si * A.y;
                Yi += Si * A.x - Sr * A.y;
            }
        }
        yw[hl][l] = make_float2(Yr, Yi);
        __syncthreads();

        int m2 = (hl * h0) & 255;
        #pragma unroll
        for (int hh = 0; hh < 16; ++hh) {
            const float2 y = yw[hh][l];
            const float2 t = tw[m2];
            zr += y.x * t.x + y.y * t.y;
            zi += y.y * t.x - y.x * t.y;
            m2 = (m2 + hl) & 255;
        }
    }

    const float sc = 1.0f / 256.0f;
    const int idx = (gb * NC + c) * 256 + tid;
    zred[idx * 2 + 0] = zr * sc;
    zred[idx * 2 + 1] = zi * sc;
}

// ---------------------------------------------------------------------------
// Mode mix v2: grid (oc=32, mq=4, g=G) = full-device weight streaming.
// block 256 = 4 i-chunks x 64 modes; LDS reduction over i-chunks.
// ---------------------------------------------------------------------------
__global__ __launch_bounds__(256) void mix_kernel(
    const float* __restrict__ zred,
    float* __restrict__ zmix,
    const float* __restrict__ wr,
    const float* __restrict__ wi,
    int o0, int n, int zgmul)
{
    __shared__ float ps[4][NB][64][2];
    const int tid = threadIdx.x;
    const int oc = blockIdx.x, mq = blockIdx.y, g = blockIdx.z;
    const int o = o0 + g, zg = zgmul * g;
    const int ichunk = tid >> 6, ml = tid & 63;
    const int mode = mq * 64 + ml;

    const float* wrb = wr + (size_t)(o * 4 + n) * NC * NC * 256;
    const float* wib = wi + (size_t)(o * 4 + n) * NC * NC * 256;

    float orr[NB] = {0.f, 0.f, 0.f, 0.f};
    float oii[NB] = {0.f, 0.f, 0.f, 0.f};

    #pragma unroll
    for (int ii = 0; ii < 8; ++ii) {
        const int i = ichunk * 8 + ii;
        const float wrv = wrb[(i * NC + oc) * 256 + mode];
        const float wiv = wib[(i * NC + oc) * 256 + mode];
        #pragma unroll
        for (int b = 0; b < NB; ++b) {
            const float2 z = *(const float2*)&zred[(((zg * NB + b) * NC + i) * 256 + mode) * 2];
            orr[b] += z.x * wrv - z.y * wiv;
            oii[b] += z.x * wiv + z.y * wrv;
        }
    }
    #pragma unroll
    for (int b = 0; b < NB; ++b) {
        ps[ichunk][b][ml][0] = orr[b];
        ps[ichunk][b][ml][1] = oii[b];
    }
    __syncthreads();

    const int b2 = tid >> 6, ml2 = tid & 63;
    float re = 0.f, im = 0.f;
    #pragma unroll
    for (int ic = 0; ic < 4; ++ic) {
        re += ps[ic][b2][ml2][0];
        im += ps[ic][b2][ml2][1];
    }
    const int oidx = ((g * NB + b2) * NC + oc) * 256 + mq * 64 + ml2;
    zmix[oidx * 2 + 0] = re;
    zmix[oidx * 2 + 1] = im;
}

// ---------------------------------------------------------------------------
// Inverse transform + bypass + GELU (+ fused projection), split-bf16 MFMA.
// Per block (h, gb): phase A builds T[c][kk] (kk: 0-15 re, 16-31 -im; bias
// folded into T[c][0]); two K=32 GEMMs (spectral T*CW + bypass BW*X) run as
// 16x16x32 MFMA tiles, hi/lo split (3 products each); epilogue = GELU(+proj).
// grid: (h=256, gb=G*4), block 256 (4 waves; wave wv owns n-tiles wv*4..+3).
// ---------------------------------------------------------------------------
template<bool LIFT, bool FINAL>
__global__ __launch_bounds__(256) void inv_kernel(
    const float* __restrict__ zmix,
    const float* __restrict__ src,
    const float* __restrict__ byp_w,
    const float* __restrict__ byp_b,
    const float* __restrict__ lift_w,
    const float* __restrict__ lift_b,
    const float* __restrict__ proj_w,
    const float* __restrict__ proj_b,
    const u16* __restrict__ cwhi,
    const u16* __restrict__ cwlo,
    float* __restrict__ dst,
    int o0, int n)
{
    __shared__ float2 tw[256];
    __shared__ u16 Thi[NC * 40], Tlo[NC * 40];   // A-operand, stride 40 (16B-aligned, bank-spread)
    __shared__ u16 Whi[NC * 40], Wlo[NC * 40];
    __shared__ float bbl[NC];
    __shared__ float bweffs[NC * 3];

    const int tid = threadIdx.x;
    const int h = blockIdx.x;
    const int gb = blockIdx.y;
    const int g = gb >> 2, b = gb & 3;
    const int o = o0 + g;

    {
        float s, cs;
        sincospif((float)tid * (2.0f / 256.0f), &s, &cs);
        tw[tid] = make_float2(cs, s);
    }

    const float* bwp = byp_w + (size_t)(o * 4 + n) * NC * NC;
    const float* bbp = byp_b + (o * 4 + n) * NC;

    if (LIFT) {
        if (tid < 96) {
            const int oc = tid / 3, j = tid % 3;
            float s = 0.f;
            for (int ic = 0; ic < NC; ++ic) s += bwp[oc * NC + ic] * lift_w[ic * 3 + j];
            bweffs[oc * 3 + j] = s;
        } else if (tid < 128) {
            const int oc = tid - 96;
            float s = bbp[oc];
            for (int ic = 0; ic < NC; ++ic) s += bwp[oc * NC + ic] * lift_b[ic];
            bbl[oc] = s;
        }
    } else {
        if (tid < NC) bbl[tid] = bbp[tid];
    }
    __syncthreads();

    // stage bypass weights (split) into A-layout LDS
    for (int idx = tid; idx < NC * NC; idx += 256) {
        const int c = idx >> 5, ic = idx & 31;
        float v;
        if (LIFT) v = (ic < 3) ? bweffs[c * 3 + ic] : 0.f;
        else      v = bwp[idx];
        const u16 hi = f2bf(v);
        Whi[c * 40 + ic] = hi;
        Wlo[c * 40 + ic] = f2bf(v - bf2f(hi));
    }

    // phase A: T[c][l] = sl * sum_k Z[c,k,l] * e^{+2pi i k h/256}; bias into T[c][0]
    #pragma unroll
    for (int rep = 0; rep < 2; ++rep) {
        const int it = rep * 256 + tid;
        const int c = it >> 4, l = it & 15;
        const float sl = (l == 0 ? 1.0f : 2.0f) / 256.0f;
        const float* zp = zmix + ((size_t)(gb * NC + c) * 256 + l) * 2;
        float tr = 0.f, ti = 0.f;
        int m = 0;
        #pragma unroll
        for (int k = 0; k < NM; ++k) {
            const float2 z = *(const float2*)(zp + k * 32);
            const float2 t = tw[m];
            tr += z.x * t.x - z.y * t.y;
            ti += z.x * t.y + z.y * t.x;
            m = (m + h) & 255;
        }
        tr *= sl; ti *= sl;
        if (l == 0) tr += bbl[c];
        const u16 rh = f2bf(tr);
        Thi[c * 40 + l] = rh;
        Tlo[c * 40 + l] = f2bf(tr - bf2f(rh));
        const float nti_ = -ti;
        const u16 ih = f2bf(nti_);
        Thi[c * 40 + 16 + l] = ih;
        Tlo[c * 40 + 16 + l] = f2bf(nti_ - bf2f(ih));
    }
    __syncthreads();

    // MFMA phase
    const int lane = tid & 63, wv = tid >> 6;
    const int mrow = lane & 15, q = lane >> 4;

    bf16x8 aThi[2], aTlo[2], aWhi[2], aWlo[2];
    #pragma unroll
    for (int mt = 0; mt < 2; ++mt) {
        const int ro = (mt * 16 + mrow) * 40 + 8 * q;
        aThi[mt] = *(const bf16x8*)&Thi[ro];
        aTlo[mt] = *(const bf16x8*)&Tlo[ro];
        aWhi[mt] = *(const bf16x8*)&Whi[ro];
        aWlo[mt] = *(const bf16x8*)&Wlo[ro];
    }

    float pwv[8];
    float pb = 0.f;
    if (FINAL) {
        #pragma unroll
        for (int mt = 0; mt < 2; ++mt)
            #pragma unroll
            for (int i = 0; i < 4; ++i)
                pwv[mt * 4 + i] = proj_w[mt * 16 + q * 4 + i];
        pb = proj_b[0];
    }

    const float* xb = src + (LIFT ? (size_t)b * 3 * NPIX : (size_t)gb * NC * NPIX) + h * NW;
    const int KIC = LIFT ? 3 : NC;

    for (int nti = 0; nti < 4; ++nti) {
        const int nt = wv * 4 + nti;
        const int ncol = nt * 16 + mrow;

        const bf16x8 cwh = *(const bf16x8*)(cwhi + ncol * 32 + 8 * q);
        const bf16x8 cwl = *(const bf16x8*)(cwlo + ncol * 32 + 8 * q);

        bf16x8 xh, xl;
        #pragma unroll
        for (int j = 0; j < 8; ++j) {
            const int k = 8 * q + j;
            const float v = (k < KIC) ? xb[(size_t)k * NPIX + ncol] : 0.f;
            const u16 hi = f2bf(v);
            xh[j] = (short)hi;
            xl[j] = (short)f2bf(v - bf2f(hi));
        }

        float fpart = 0.f;
        #pragma unroll
        for (int mt = 0; mt < 2; ++mt) {
            f32x4 acc = {0.f, 0.f, 0.f, 0.f};
            acc = MFMA16(aThi[mt], cwh, acc);
            acc = MFMA16(aThi[mt], cwl, acc);
            acc = MFMA16(aTlo[mt], cwh, acc);
            acc = MFMA16(aWhi[mt], xh, acc);
            acc = MFMA16(aWhi[mt], xl, acc);
            acc = MFMA16(aWlo[mt], xh, acc);
            if (FINAL) {
                #pragma unroll
                for (int i = 0; i < 4; ++i)
                    fpart += gelu_fast(acc[i]) * pwv[mt * 4 + i];
            } else {
                #pragma unroll
                for (int i = 0; i < 4; ++i) {
                    const int c = mt * 16 + q * 4 + i;
                    dst[((size_t)gb * NC + c) * NPIX + h * NW + ncol] = gelu_fast(acc[i]);
                }
            }
        }
        if (FINAL) {
            fpart += __shfl_xor(fpart, 16);
            fpart += __shfl_xor(fpart, 32);
            if (q == 0) {
                dst[(((size_t)b * 4 + o) * NH + h) * NW + nt * 16 + mrow] = fpart + pb;
            }
        }
    }
}

// ---------------------------------------------------------------------------
extern "C" void kernel_launch(void* const* d_in, const int* in_sizes, int n_in,
                              void* d_out, int out_size, void* d_ws, size_t ws_size,
                              hipStream_t stream)
{
    const float* x      = (const float*)d_in[0];
    const float* lift_w = (const float*)d_in[1];
    const float* lift_b = (const float*)d_in[2];
    const float* wr     = (const float*)d_in[3];
    const float* wi     = (const float*)d_in[4];
    const float* byp_w  = (const float*)d_in[5];
    const float* byp_b  = (const float*)d_in[6];
    const float* proj_w = (const float*)d_in[7];
    const float* proj_b = (const float*)d_in[8];
    float* out = (float*)d_out;
    float* ws  = (float*)d_ws;

    // ws: [cwhi 8192 u16][cwlo 8192 u16] (=8192 floats) | bufA | bufB | zred | zmix
    u16* cwhi = (u16*)ws;
    u16* cwlo = cwhi + 8192;
    float* base = ws + 8192;

    int G = 4;
    while (G > 1) {
        const size_t need = (8192 + (size_t)2 * G * NP + (size_t)2 * G * ZG) * sizeof(float);
        if (need <= ws_size) break;
        G >>= 1;
    }

    float* bufA = base;
    float* bufB = bufA + (size_t)G * NP;
    float* zred = bufB + (size_t)G * NP;
    float* zmix = zred + (size_t)G * ZG;

    cw_prep<<<32, 256, 0, stream>>>(cwhi, cwlo);

    for (int o0 = 0; o0 < 4; o0 += G) {
        const float* rd = nullptr;
        float* wrbuf = bufA;
        for (int n = 0; n < 4; ++n) {
            const bool lift = (n == 0);
            const bool fin  = (n == 3);
            const float* src = lift ? x : rd;

            if (lift) {
                fwd_kernel<true><<<dim3(NC, NB), 256, 0, stream>>>(src, lift_w, lift_b, zred);
            } else {
                fwd_kernel<false><<<dim3(NC, G * NB), 256, 0, stream>>>(src, lift_w, lift_b, zred);
            }

            mix_kernel<<<dim3(NC, 4, G), 256, 0, stream>>>(zred, zmix, wr, wi, o0, n, lift ? 0 : 1);

            dim3 igrid(NH, G * NB);
            if (fin) {
                inv_kernel<false, true><<<igrid, 256, 0, stream>>>(
                    zmix, src, byp_w, byp_b, lift_w, lift_b, proj_w, proj_b, cwhi, cwlo, out, o0, n);
            } else if (lift) {
                inv_kernel<true, false><<<igrid, 256, 0, stream>>>(
                    zmix, src, byp_w, byp_b, lift_w, lift_b, proj_w, proj_b, cwhi, cwlo, wrbuf, o0, n);
            } else {
                inv_kernel<false, false><<<igrid, 256, 0, stream>>>(
                    zmix, src, byp_w, byp_b, lift_w, lift_b, proj_w, proj_b, cwhi, cwlo, wrbuf, o0, n);
            }
            rd = wrbuf;
            wrbuf = (wrbuf == bufA) ? bufB : bufA;
        }
    }
}

// Round 4
// 547.736 us; speedup vs baseline: 2.3142x; 1.4377x over previous
//
#include <hip/hip_runtime.h>

#define NB 4      // batch
#define NC 32     // width (channels)
#define NH 256
#define NW 256
#define NM 16     // modes per dim
constexpr int NPIX = NH * NW;                 // 65536
constexpr int NP = NB * NC * NPIX;            // floats per per-o tensor
constexpr int ZG = NB * NC * NM * NM * 2;     // floats per g for zred/zmix (65536)

typedef short bf16x8 __attribute__((ext_vector_type(8)));
typedef float f32x4  __attribute__((ext_vector_type(4)));
typedef unsigned short u16;

#define MFMA16(a, b, c) __builtin_amdgcn_mfma_f32_16x16x32_bf16(a, b, c, 0, 0, 0)

__device__ __forceinline__ u16 f2bf(float f) {
    unsigned u = __float_as_uint(f);
    u += 0x7FFFu + ((u >> 16) & 1u);
    return (u16)(u >> 16);
}
__device__ __forceinline__ float bf2f(u16 h) {
    return __uint_as_float(((unsigned)h) << 16);
}

// fast erf (A&S 7.1.26, |err| <= 1.5e-7) based exact-GELU
__device__ __forceinline__ float gelu_fast(float v) {
    const float ax = fabsf(v) * 0.70710678118654752f;
    const float t = __builtin_amdgcn_rcpf(1.0f + 0.3275911f * ax);
    const float y = t * (0.254829592f + t * (-0.284496736f + t * (1.421413741f +
                    t * (-1.453152027f + t * 1.061405429f))));
    const float e = __expf(-ax * ax);
    float er = 1.0f - y * e;
    er = copysignf(er, v);
    return 0.5f * v * (1.0f + er);
}

// ---------------------------------------------------------------------------
// CW prep (inv B-operand): [n=256][k=32], k<16: cos(2pi*k*n/256), k>=16: sin.
// ---------------------------------------------------------------------------
__global__ __launch_bounds__(256) void cw_prep(u16* __restrict__ cwhi, u16* __restrict__ cwlo) {
    const int id = blockIdx.x * 256 + threadIdx.x;
    const int nn = id >> 5, k = id & 31;
    const int m = ((k & 15) * nn) & 255;
    float s, c;
    sincospif((float)m * (2.0f / 256.0f), &s, &c);
    const float v = (k < 16) ? c : s;
    const u16 hi = f2bf(v);
    cwhi[id] = hi;
    cwlo[id] = f2bf(v - bf2f(hi));
}

// ---------------------------------------------------------------------------
// EB prep (fwd stage-1 B-operand AND stage-2 A-operand): [row=32][w=256],
// row<16: cos(2pi*row*w/256)/16, row>=16: sin(2pi*(row-16)*w/256)/16.
// The 1/16 applies once per stage -> 1/256 total (ortho rfft2 norm).
// ---------------------------------------------------------------------------
__global__ __launch_bounds__(256) void eb_prep(u16* __restrict__ ebhi, u16* __restrict__ eblo) {
    const int id = blockIdx.x * 256 + threadIdx.x;
    const int row = id >> 8, w = id & 255;
    const int m = ((row & 15) * w) & 255;
    float s, c;
    sincospif((float)m * (2.0f / 256.0f), &s, &c);
    const float v = 0.0625f * ((row < 16) ? c : s);
    const u16 hi = f2bf(v);
    ebhi[id] = hi;
    eblo[id] = f2bf(v - bf2f(hi));
}

// ---------------------------------------------------------------------------
// Forward truncated DFT, split-bf16 MFMA, 2-stage per block (c, gb).
// Stage 1: Y[h, 32] = X[h, w] * EB^T  (wave wv owns rows [wv*32, wv*32+32))
// Stage 2: P[32,32] = EB * Y (waves 0-3, one 16x16 tile each)
// Combine: Zr = Pcc - Pss, Zi = -(Pcs + Psc); write zred.
// grid: (32, LIFT ? 4 : G*4), block 512.
// ---------------------------------------------------------------------------
template<bool LIFT>
__global__ __launch_bounds__(512) void fwd_kernel(
    const float* __restrict__ src,
    const float* __restrict__ lift_w,
    const float* __restrict__ lift_b,
    const u16* __restrict__ ebhi,
    const u16* __restrict__ eblo,
    float* __restrict__ zred)
{
    __shared__ u16 Yhi[32 * 260], Ylo[32 * 260];   // [combo][h], pad 260
    __shared__ float P[32][33];

    const int tid = threadIdx.x;
    const int c  = blockIdx.x;
    const int gb = blockIdx.y;          // LIFT: gb == b
    const int b  = gb & 3;
    const int wv = tid >> 6, lane = tid & 63;
    const int mrow = lane & 15, q = lane >> 4;

    float lw0 = 0.f, lw1 = 0.f, lw2 = 0.f, lb = 0.f;
    const float* sb;
    if (LIFT) {
        lw0 = lift_w[c * 3 + 0]; lw1 = lift_w[c * 3 + 1]; lw2 = lift_w[c * 3 + 2];
        lb = lift_b[c];
        sb = src + (size_t)b * 3 * NPIX;
    } else {
        sb = src + ((size_t)gb * NC + c) * NPIX;
    }

    // ---- stage 1 ----
    f32x4 acc[2][2] = {};
    for (int ks = 0; ks < 8; ++ks) {
        bf16x8 bh[2], bl[2];
        #pragma unroll
        for (int nt = 0; nt < 2; ++nt) {
            const int off = (nt * 16 + mrow) * 256 + ks * 32 + q * 8;
            bh[nt] = *(const bf16x8*)(ebhi + off);
            bl[nt] = *(const bf16x8*)(eblo + off);
        }
        #pragma unroll
        for (int mt = 0; mt < 2; ++mt) {
            const int h = wv * 32 + mt * 16 + mrow;
            const float* xp = sb + (size_t)h * NW + ks * 32 + q * 8;
            float v[8];
            if (LIFT) {
                const float4 p0a = *(const float4*)(xp);
                const float4 p0b = *(const float4*)(xp + 4);
                const float4 p1a = *(const float4*)(xp + NPIX);
                const float4 p1b = *(const float4*)(xp + NPIX + 4);
                const float4 p2a = *(const float4*)(xp + 2 * NPIX);
                const float4 p2b = *(const float4*)(xp + 2 * NPIX + 4);
                v[0] = lw0 * p0a.x + lw1 * p1a.x + lw2 * p2a.x + lb;
                v[1] = lw0 * p0a.y + lw1 * p1a.y + lw2 * p2a.y + lb;
                v[2] = lw0 * p0a.z + lw1 * p1a.z + lw2 * p2a.z + lb;
                v[3] = lw0 * p0a.w + lw1 * p1a.w + lw2 * p2a.w + lb;
                v[4] = lw0 * p0b.x + lw1 * p1b.x + lw2 * p2b.x + lb;
                v[5] = lw0 * p0b.y + lw1 * p1b.y + lw2 * p2b.y + lb;
                v[6] = lw0 * p0b.z + lw1 * p1b.z + lw2 * p2b.z + lb;
                v[7] = lw0 * p0b.w + lw1 * p1b.w + lw2 * p2b.w + lb;
            } else {
                const float4 pa = *(const float4*)(xp);
                const float4 pb = *(const float4*)(xp + 4);
                v[0] = pa.x; v[1] = pa.y; v[2] = pa.z; v[3] = pa.w;
                v[4] = pb.x; v[5] = pb.y; v[6] = pb.z; v[7] = pb.w;
            }
            bf16x8 xh, xl;
            #pragma unroll
            for (int j = 0; j < 8; ++j) {
                const u16 hi = f2bf(v[j]);
                xh[j] = (short)hi;
                xl[j] = (short)f2bf(v[j] - bf2f(hi));
            }
            #pragma unroll
            for (int nt = 0; nt < 2; ++nt) {
                acc[mt][nt] = MFMA16(xh, bh[nt], acc[mt][nt]);
                acc[mt][nt] = MFMA16(xh, bl[nt], acc[mt][nt]);
                acc[mt][nt] = MFMA16(xl, bh[nt], acc[mt][nt]);
            }
        }
    }

    // write Y (C-layout -> [combo][h] split-bf16 LDS)
    #pragma unroll
    for (int mt = 0; mt < 2; ++mt) {
        #pragma unroll
        for (int nt = 0; nt < 2; ++nt) {
            #pragma unroll
            for (int r = 0; r < 4; ++r) {
                const int h = wv * 32 + mt * 16 + q * 4 + r;
                const int combo = nt * 16 + mrow;
                const float val = acc[mt][nt][r];
                const u16 hi = f2bf(val);
                Yhi[combo * 260 + h] = hi;
                Ylo[combo * 260 + h] = f2bf(val - bf2f(hi));
            }
        }
    }
    __syncthreads();

    // ---- stage 2 (waves 0-3) ----
    if (wv < 4) {
        const int mt2 = wv >> 1, nt2 = wv & 1;
        f32x4 p = {};
        for (int ks = 0; ks < 8; ++ks) {
            const int aoff = (mt2 * 16 + mrow) * 256 + ks * 32 + q * 8;
            const bf16x8 ah = *(const bf16x8*)(ebhi + aoff);
            const bf16x8 al = *(const bf16x8*)(eblo + aoff);
            const int boff = (nt2 * 16 + mrow) * 260 + ks * 32 + q * 8;
            const bf16x8 yh = *(const bf16x8*)(Yhi + boff);
            const bf16x8 yl = *(const bf16x8*)(Ylo + boff);
            p = MFMA16(ah, yh, p);
            p = MFMA16(ah, yl, p);
            p = MFMA16(al, yh, p);
        }
        #pragma unroll
        for (int r = 0; r < 4; ++r)
            P[mt2 * 16 + q * 4 + r][nt2 * 16 + mrow] = p[r];
    }
    __syncthreads();

    // ---- combine + store ----
    if (tid < 256) {
        const int k = tid >> 4, l = tid & 15;
        const float zr = P[k][l] - P[16 + k][16 + l];
        const float zi = -(P[k][16 + l] + P[16 + k][l]);
        const int idx = (gb * NC + c) * 256 + tid;
        zred[idx * 2 + 0] = zr;
        zred[idx * 2 + 1] = zi;
    }
}

// ---------------------------------------------------------------------------
// Mode mix: grid (oc=32, mq=4, g=G); block 256 = 4 i-chunks x 64 modes.
// ---------------------------------------------------------------------------
__global__ __launch_bounds__(256) void mix_kernel(
    const float* __restrict__ zred,
    float* __restrict__ zmix,
    const float* __restrict__ wr,
    const float* __restrict__ wi,
    int o0, int n, int zgmul)
{
    __shared__ float ps[4][NB][64][2];
    const int tid = threadIdx.x;
    const int oc = blockIdx.x, mq = blockIdx.y, g = blockIdx.z;
    const int o = o0 + g, zg = zgmul * g;
    const int ichunk = tid >> 6, ml = tid & 63;
    const int mode = mq * 64 + ml;

    const float* wrb = wr + (size_t)(o * 4 + n) * NC * NC * 256;
    const float* wib = wi + (size_t)(o * 4 + n) * NC * NC * 256;

    float orr[NB] = {0.f, 0.f, 0.f, 0.f};
    float oii[NB] = {0.f, 0.f, 0.f, 0.f};

    #pragma unroll
    for (int ii = 0; ii < 8; ++ii) {
        const int i = ichunk * 8 + ii;
        const float wrv = wrb[(i * NC + oc) * 256 + mode];
        const float wiv = wib[(i * NC + oc) * 256 + mode];
        #pragma unroll
        for (int b = 0; b < NB; ++b) {
            const float2 z = *(const float2*)&zred[(((zg * NB + b) * NC + i) * 256 + mode) * 2];
            orr[b] += z.x * wrv - z.y * wiv;
            oii[b] += z.x * wiv + z.y * wrv;
        }
    }
    #pragma unroll
    for (int b = 0; b < NB; ++b) {
        ps[ichunk][b][ml][0] = orr[b];
        ps[ichunk][b][ml][1] = oii[b];
    }
    __syncthreads();

    const int b2 = tid >> 6, ml2 = tid & 63;
    float re = 0.f, im = 0.f;
    #pragma unroll
    for (int ic = 0; ic < 4; ++ic) {
        re += ps[ic][b2][ml2][0];
        im += ps[ic][b2][ml2][1];
    }
    const int oidx = ((g * NB + b2) * NC + oc) * 256 + mq * 64 + ml2;
    zmix[oidx * 2 + 0] = re;
    zmix[oidx * 2 + 1] = im;
}

// ---------------------------------------------------------------------------
// Inverse transform + bypass + GELU (+ fused projection), split-bf16 MFMA.
// grid: (h=256, gb=G*4), block 256.
// ---------------------------------------------------------------------------
template<bool LIFT, bool FINAL>
__global__ __launch_bounds__(256) void inv_kernel(
    const float* __restrict__ zmix,
    const float* __restrict__ src,
    const float* __restrict__ byp_w,
    const float* __restrict__ byp_b,
    const float* __restrict__ lift_w,
    const float* __restrict__ lift_b,
    const float* __restrict__ proj_w,
    const float* __restrict__ proj_b,
    const u16* __restrict__ cwhi,
    const u16* __restrict__ cwlo,
    float* __restrict__ dst,
    int o0, int n)
{
    __shared__ float2 tw[256];
    __shared__ u16 Thi[NC * 40], Tlo[NC * 40];
    __shared__ u16 Whi[NC * 40], Wlo[NC * 40];
    __shared__ float bbl[NC];
    __shared__ float bweffs[NC * 3];

    const int tid = threadIdx.x;
    const int h = blockIdx.x;
    const int gb = blockIdx.y;
    const int g = gb >> 2, b = gb & 3;
    const int o = o0 + g;

    {
        float s, cs;
        sincospif((float)tid * (2.0f / 256.0f), &s, &cs);
        tw[tid] = make_float2(cs, s);
    }

    const float* bwp = byp_w + (size_t)(o * 4 + n) * NC * NC;
    const float* bbp = byp_b + (o * 4 + n) * NC;

    if (LIFT) {
        if (tid < 96) {
            const int oc = tid / 3, j = tid % 3;
            float s = 0.f;
            for (int ic = 0; ic < NC; ++ic) s += bwp[oc * NC + ic] * lift_w[ic * 3 + j];
            bweffs[oc * 3 + j] = s;
        } else if (tid < 128) {
            const int oc = tid - 96;
            float s = bbp[oc];
            for (int ic = 0; ic < NC; ++ic) s += bwp[oc * NC + ic] * lift_b[ic];
            bbl[oc] = s;
        }
    } else {
        if (tid < NC) bbl[tid] = bbp[tid];
    }
    __syncthreads();

    for (int idx = tid; idx < NC * NC; idx += 256) {
        const int c = idx >> 5, ic = idx & 31;
        float v;
        if (LIFT) v = (ic < 3) ? bweffs[c * 3 + ic] : 0.f;
        else      v = bwp[idx];
        const u16 hi = f2bf(v);
        Whi[c * 40 + ic] = hi;
        Wlo[c * 40 + ic] = f2bf(v - bf2f(hi));
    }

    #pragma unroll
    for (int rep = 0; rep < 2; ++rep) {
        const int it = rep * 256 + tid;
        const int c = it >> 4, l = it & 15;
        const float sl = (l == 0 ? 1.0f : 2.0f) / 256.0f;
        const float* zp = zmix + ((size_t)(gb * NC + c) * 256 + l) * 2;
        float tr = 0.f, ti = 0.f;
        int m = 0;
        #pragma unroll
        for (int k = 0; k < NM; ++k) {
            const float2 z = *(const float2*)(zp + k * 32);
            const float2 t = tw[m];
            tr += z.x * t.x - z.y * t.y;
            ti += z.x * t.y + z.y * t.x;
            m = (m + h) & 255;
        }
        tr *= sl; ti *= sl;
        if (l == 0) tr += bbl[c];
        const u16 rh = f2bf(tr);
        Thi[c * 40 + l] = rh;
        Tlo[c * 40 + l] = f2bf(tr - bf2f(rh));
        const float nti_ = -ti;
        const u16 ih = f2bf(nti_);
        Thi[c * 40 + 16 + l] = ih;
        Tlo[c * 40 + 16 + l] = f2bf(nti_ - bf2f(ih));
    }
    __syncthreads();

    const int lane = tid & 63, wv = tid >> 6;
    const int mrow = lane & 15, q = lane >> 4;

    bf16x8 aThi[2], aTlo[2], aWhi[2], aWlo[2];
    #pragma unroll
    for (int mt = 0; mt < 2; ++mt) {
        const int ro = (mt * 16 + mrow) * 40 + 8 * q;
        aThi[mt] = *(const bf16x8*)&Thi[ro];
        aTlo[mt] = *(const bf16x8*)&Tlo[ro];
        aWhi[mt] = *(const bf16x8*)&Whi[ro];
        aWlo[mt] = *(const bf16x8*)&Wlo[ro];
    }

    float pwv[8];
    float pb = 0.f;
    if (FINAL) {
        #pragma unroll
        for (int mt = 0; mt < 2; ++mt)
            #pragma unroll
            for (int i = 0; i < 4; ++i)
                pwv[mt * 4 + i] = proj_w[mt * 16 + q * 4 + i];
        pb = proj_b[0];
    }

    const float* xb = src + (LIFT ? (size_t)b * 3 * NPIX : (size_t)gb * NC * NPIX) + h * NW;
    const int KIC = LIFT ? 3 : NC;

    for (int nti = 0; nti < 4; ++nti) {
        const int nt = wv * 4 + nti;
        const int ncol = nt * 16 + mrow;

        const bf16x8 cwh = *(const bf16x8*)(cwhi + ncol * 32 + 8 * q);
        const bf16x8 cwl = *(const bf16x8*)(cwlo + ncol * 32 + 8 * q);

        bf16x8 xh, xl;
        #pragma unroll
        for (int j = 0; j < 8; ++j) {
            const int k = 8 * q + j;
            const float v = (k < KIC) ? xb[(size_t)k * NPIX + ncol] : 0.f;
            const u16 hi = f2bf(v);
            xh[j] = (short)hi;
            xl[j] = (short)f2bf(v - bf2f(hi));
        }

        float fpart = 0.f;
        #pragma unroll
        for (int mt = 0; mt < 2; ++mt) {
            f32x4 acc = {0.f, 0.f, 0.f, 0.f};
            acc = MFMA16(aThi[mt], cwh, acc);
            acc = MFMA16(aThi[mt], cwl, acc);
            acc = MFMA16(aTlo[mt], cwh, acc);
            acc = MFMA16(aWhi[mt], xh, acc);
            acc = MFMA16(aWhi[mt], xl, acc);
            acc = MFMA16(aWlo[mt], xh, acc);
            if (FINAL) {
                #pragma unroll
                for (int i = 0; i < 4; ++i)
                    fpart += gelu_fast(acc[i]) * pwv[mt * 4 + i];
            } else {
                #pragma unroll
                for (int i = 0; i < 4; ++i) {
                    const int c = mt * 16 + q * 4 + i;
                    dst[((size_t)gb * NC + c) * NPIX + h * NW + ncol] = gelu_fast(acc[i]);
                }
            }
        }
        if (FINAL) {
            fpart += __shfl_xor(fpart, 16);
            fpart += __shfl_xor(fpart, 32);
            if (q == 0) {
                dst[(((size_t)b * 4 + o) * NH + h) * NW + nt * 16 + mrow] = fpart + pb;
            }
        }
    }
}

// ---------------------------------------------------------------------------
extern "C" void kernel_launch(void* const* d_in, const int* in_sizes, int n_in,
                              void* d_out, int out_size, void* d_ws, size_t ws_size,
                              hipStream_t stream)
{
    const float* x      = (const float*)d_in[0];
    const float* lift_w = (const float*)d_in[1];
    const float* lift_b = (const float*)d_in[2];
    const float* wr     = (const float*)d_in[3];
    const float* wi     = (const float*)d_in[4];
    const float* byp_w  = (const float*)d_in[5];
    const float* byp_b  = (const float*)d_in[6];
    const float* proj_w = (const float*)d_in[7];
    const float* proj_b = (const float*)d_in[8];
    float* out = (float*)d_out;
    float* ws  = (float*)d_ws;

    // ws: [cwhi|cwlo|ebhi|eblo : 4 x 8192 u16 = 16384 floats] | bufA | bufB | zred | zmix
    u16* cwhi = (u16*)ws;
    u16* cwlo = cwhi + 8192;
    u16* ebhi = cwlo + 8192;
    u16* eblo = ebhi + 8192;
    float* base = ws + 16384;

    int G = 4;
    while (G > 1) {
        const size_t need = (16384 + (size_t)2 * G * NP + (size_t)2 * G * ZG) * sizeof(float);
        if (need <= ws_size) break;
        G >>= 1;
    }

    float* bufA = base;
    float* bufB = bufA + (size_t)G * NP;
    float* zred = bufB + (size_t)G * NP;
    float* zmix = zred + (size_t)G * ZG;

    cw_prep<<<32, 256, 0, stream>>>(cwhi, cwlo);
    eb_prep<<<32, 256, 0, stream>>>(ebhi, eblo);

    for (int o0 = 0; o0 < 4; o0 += G) {
        const float* rd = nullptr;
        float* wrbuf = bufA;
        for (int n = 0; n < 4; ++n) {
            const bool lift = (n == 0);
            const bool fin  = (n == 3);
            const float* src = lift ? x : rd;

            if (lift) {
                fwd_kernel<true><<<dim3(NC, NB), 512, 0, stream>>>(src, lift_w, lift_b, ebhi, eblo, zred);
            } else {
                fwd_kernel<false><<<dim3(NC, G * NB), 512, 0, stream>>>(src, lift_w, lift_b, ebhi, eblo, zred);
            }

            mix_kernel<<<dim3(NC, 4, G), 256, 0, stream>>>(zred, zmix, wr, wi, o0, n, lift ? 0 : 1);

            dim3 igrid(NH, G * NB);
            if (fin) {
                inv_kernel<false, true><<<igrid, 256, 0, stream>>>(
                    zmix, src, byp_w, byp_b, lift_w, lift_b, proj_w, proj_b, cwhi, cwlo, out, o0, n);
            } else if (lift) {
                inv_kernel<true, false><<<igrid, 256, 0, stream>>>(
                    zmix, src, byp_w, byp_b, lift_w, lift_b, proj_w, proj_b, cwhi, cwlo, wrbuf, o0, n);
            } else {
                inv_kernel<false, false><<<igrid, 256, 0, stream>>>(
                    zmix, src, byp_w, byp_b, lift_w, lift_b, proj_w, proj_b, cwhi, cwlo, wrbuf, o0, n);
            }
            rd = wrbuf;
            wrbuf = (wrbuf == bufA) ? bufB : bufA;
        }
    }
}